// Round 3
// baseline (15.872 us; speedup 1.0000x reference)
//
#include <hip/hip_runtime.h>
#include <hip/hip_bf16.h>

// Pooler ragged-mean: out[b,s,:] = mean(features[b, begins[b,s]:ends[b,s], :])
// B=8, T=4096, D=256, S=1024, MAX_W=32. Empty spans -> 0.
//
// One 64-lane wave per span; lane owns 4 channels (float4). 4 waves/block.
// XCD swizzle: batch b -> XCD b (features[b] = 4 MB = one XCD's L2).
// High-MLP inner loop: 16 unconditional loads (min-clamped row) in flight,
// then predicated accumulate; second guarded 16-chunk for w>16.

#define B_DIM 8
#define T_DIM 4096
#define D_DIM 256
#define S_DIM 1024
#define MAX_W 32
#define NXCD 8

__global__ __launch_bounds__(256) void pooler_kernel(
    const float* __restrict__ features,   // [B, T, D]
    const int*   __restrict__ begins,     // [B, S]
    const int*   __restrict__ ends,       // [B, S]
    float*       __restrict__ out)        // [B, S, D]
{
    const int phys = blockIdx.x;
    const int lblk = (phys & (NXCD - 1)) * (2048 / NXCD) + (phys >> 3);

    const int span = lblk * 4 + (threadIdx.x >> 6);  // [0, B*S)
    const int lane = threadIdx.x & 63;
    const int b = span >> 10;  // S_DIM = 1024

    int begin = begins[span];
    int end   = ends[span];
    begin = begin > 0 ? begin : 0;
    end   = end   > 0 ? end   : 0;
    end   = end   < T_DIM ? end : T_DIM;   // rows in-range; hoists per-iter clamp
    int w = end - begin;
    w = w < MAX_W ? w : MAX_W;

    float4* outp = reinterpret_cast<float4*>(out + (size_t)span * D_DIM) + lane;

    if (w <= 0) {
        *outp = make_float4(0.f, 0.f, 0.f, 0.f);
        return;
    }

    const float4* p = reinterpret_cast<const float4*>(
        features + (size_t)b * T_DIM * D_DIM + (size_t)begin * D_DIM) + lane;
    const int wm1 = w - 1;

    float4 v[16];
    float4 acc = make_float4(0.f, 0.f, 0.f, 0.f);

    // chunk 0: rows 0..15, unconditional loads (row index clamped to w-1)
    #pragma unroll
    for (int j = 0; j < 16; ++j) {
        const int jj = j < wm1 ? j : wm1;
        v[j] = p[(size_t)jj * (D_DIM / 4)];
    }
    #pragma unroll
    for (int j = 0; j < 16; ++j) {
        if (j < w) { acc.x += v[j].x; acc.y += v[j].y; acc.z += v[j].z; acc.w += v[j].w; }
    }

    // chunk 1: rows 16..31, only when needed (wave-uniform guard)
    if (w > 16) {
        #pragma unroll
        for (int j = 16; j < 32; ++j) {
            const int jj = j < wm1 ? j : wm1;
            v[j - 16] = p[(size_t)jj * (D_DIM / 4)];
        }
        #pragma unroll
        for (int j = 16; j < 32; ++j) {
            if (j < w) { acc.x += v[j-16].x; acc.y += v[j-16].y; acc.z += v[j-16].z; acc.w += v[j-16].w; }
        }
    }

    const float inv = 1.0f / (float)w;
    *outp = make_float4(acc.x * inv, acc.y * inv, acc.z * inv, acc.w * inv);
}

extern "C" void kernel_launch(void* const* d_in, const int* in_sizes, int n_in,
                              void* d_out, int out_size, void* d_ws, size_t ws_size,
                              hipStream_t stream) {
    const float* features = (const float*)d_in[0];
    const int*   begins   = (const int*)d_in[1];
    const int*   ends     = (const int*)d_in[2];
    float*       out      = (float*)d_out;

    const int n_spans = B_DIM * S_DIM;            // 8192
    const int blocks  = n_spans / 4;              // 4 spans (waves) per block
    pooler_kernel<<<blocks, 256, 0, stream>>>(features, begins, ends, out);
}

// Round 5
// 14.388 us; speedup vs baseline: 1.1032x; 1.1032x over previous
//
#include <hip/hip_runtime.h>
#include <hip/hip_bf16.h>

// Pooler ragged-mean: out[b,s,:] = mean(features[b, begins[b,s]:ends[b,s], :])
// B=8, T=4096, D=256, S=1024, MAX_W=32. Empty spans -> 0.
//
// One 64-lane wave per span; lane owns 4 channels (float4). 4 waves/block.
// XCD swizzle: batch b -> XCD b (features[b] = 4 MB = one XCD's L2).
// R5 (= R4 with compile fix): conditional loop (R2 structure), hoisted row
// clamp, NONTEMPORAL output stores (native ext_vector_type — HIP float4
// is a class and the builtin rejects it) so the 8 MB output stream doesn't
// evict the pinned 4 MB feature batch from each XCD's L2.

#define B_DIM 8
#define T_DIM 4096
#define D_DIM 256
#define S_DIM 1024
#define MAX_W 32
#define NXCD 8

typedef float vfloat4 __attribute__((ext_vector_type(4)));

__global__ __launch_bounds__(256) void pooler_kernel(
    const float* __restrict__ features,   // [B, T, D]
    const int*   __restrict__ begins,     // [B, S]
    const int*   __restrict__ ends,       // [B, S]
    float*       __restrict__ out)        // [B, S, D]
{
    const int phys = blockIdx.x;
    const int lblk = (phys & (NXCD - 1)) * (2048 / NXCD) + (phys >> 3);

    const int span = lblk * 4 + (threadIdx.x >> 6);  // [0, B*S)
    const int lane = threadIdx.x & 63;
    const int b = span >> 10;  // S_DIM = 1024

    int begin = begins[span];
    int end   = ends[span];
    begin = begin > 0 ? begin : 0;
    end   = end   > 0 ? end   : 0;
    end   = end   < T_DIM ? end : T_DIM;  // => begin+j <= T-1, clamp hoisted
    int w = end - begin;
    w = w < MAX_W ? w : MAX_W;

    vfloat4* outp = reinterpret_cast<vfloat4*>(out + (size_t)span * D_DIM) + lane;

    if (w <= 0) {
        vfloat4 z = {0.f, 0.f, 0.f, 0.f};
        __builtin_nontemporal_store(z, outp);
        return;
    }

    const vfloat4* p = reinterpret_cast<const vfloat4*>(
        features + (size_t)b * T_DIM * D_DIM + (size_t)begin * D_DIM) + lane;

    vfloat4 acc = {0.f, 0.f, 0.f, 0.f};
    #pragma unroll 8
    for (int j = 0; j < w; ++j) {
        acc += p[(size_t)j * (D_DIM / 4)];
    }

    const float inv = 1.0f / (float)w;
    vfloat4 r = acc * inv;
    __builtin_nontemporal_store(r, outp);
}

extern "C" void kernel_launch(void* const* d_in, const int* in_sizes, int n_in,
                              void* d_out, int out_size, void* d_ws, size_t ws_size,
                              hipStream_t stream) {
    const float* features = (const float*)d_in[0];
    const int*   begins   = (const int*)d_in[1];
    const int*   ends     = (const int*)d_in[2];
    float*       out      = (float*)d_out;

    const int n_spans = B_DIM * S_DIM;            // 8192
    const int blocks  = n_spans / 4;              // 4 spans (waves) per block
    pooler_kernel<<<blocks, 256, 0, stream>>>(features, begins, ends, out);
}